// Round 6
// baseline (5211.469 us; speedup 1.0000x reference)
//
#include <hip/hip_runtime.h>

#define H_ 128
#define T_ 1024
#define B_ 512
#define I_ 13
#define LOG2E 1.4426950408889634f

typedef _Float16 half8 __attribute__((ext_vector_type(8)));
typedef float float4_ __attribute__((ext_vector_type(4)));

static __device__ __forceinline__ float fast_rcp(float v) {
  return __builtin_amdgcn_rcpf(v);
}
static __device__ __forceinline__ float fast_exp2(float v) {
  return __builtin_amdgcn_exp2f(v);
}
static __device__ __forceinline__ float sigmoid_f(float v) {
  return fast_rcp(1.0f + fast_exp2(-LOG2E * v));
}
static __device__ __forceinline__ float tanh_f(float v) {
  return 2.0f * fast_rcp(1.0f + fast_exp2(-2.0f * LOG2E * v)) - 1.0f;
}

// One WG per CU (256 WGs), 2 batch rows each, weights VGPR-resident.
// R6 (on the R5 zero-VMEM skeleton):
//  - xpart pipelining: acc for step t+1 is pre-charged with bias + x_{t+1}*Wih
//    at the BOTTOM of step t (xlds is read-only -> no barrier hazard). After
//    the barrier only 16 h-MFMAs sit on the critical path.
//  - FC split across waves 5 and 6 (2 K-chunks each, f16 partials in the
//    ring; phase-2 softmax sums the halves). Straggler 24 -> 22 MFMAs.
//  - loop still has ZERO vector-memory ops -> __syncthreads vmcnt drain free.
__global__ __launch_bounds__(512, 1) void lstm_fused(
    const float* __restrict__ x, const float* __restrict__ Wih,
    const float* __restrict__ Whh, const float* __restrict__ bih,
    const float* __restrict__ bhh, const float* __restrict__ Wfc,
    const float* __restrict__ bfc, float* __restrict__ out)
{
  // 64 KB: x(t) for both rows, slots 13..15 zero (pad to k-chunk width)
  __shared__ __align__(16) _Float16 xlds[T_][2][16];
  // 64 KB: logits ring, f16: [t][row][part*8 + k], parts summed in phase 2
  __shared__ __align__(16) _Float16 lgring[T_][2][16];
  // 1.3 KB: double-buffered h (cols 0..127 used; stride 168 halfs)
  __shared__ __align__(16) _Float16 abuf[2][2][168];

  const int tid  = threadIdx.x;
  const int wave = tid >> 6;
  const int lane = tid & 63;
  const int n16  = lane & 15;
  const int quad = lane >> 4;
  const int wgb  = blockIdx.x * 2;

  // ---- W fragments: wave w owns gate tiles {w, w+8, w+16, w+24} ----
  // B layout (16x16x32): lane holds B[k = quad*8 + j][n = n16]
  half8 wfrag[4][5];
  float biasv[4];
  #pragma unroll
  for (int ti = 0; ti < 4; ++ti) {
    const int col = (wave + 8 * ti) * 16 + n16;
    biasv[ti] = bih[col] + bhh[col];
    #pragma unroll
    for (int kc = 0; kc < 5; ++kc) {
      half8 f;
      #pragma unroll
      for (int j = 0; j < 8; ++j) {
        const int k = kc * 32 + quad * 8 + j;
        float v = 0.0f;
        if (k < 128)            v = Whh[col * H_ + k];
        else if (k < 128 + I_)  v = Wih[col * I_ + (k - 128)];
        f[j] = (_Float16)v;
      }
      wfrag[ti][kc] = f;
    }
  }
  // FC: wave 5 owns K-chunks 0,1 (and the bias); wave 6 owns K-chunks 2,3.
  // Loaded uniformly by all waves (others hold unused-but-valid data).
  const int fcbase = (wave == 6) ? 2 : 0;
  half8 wfc[2];
  const float biasfc = (wave == 5 && n16 < 7) ? bfc[n16] : 0.0f;
  #pragma unroll
  for (int c = 0; c < 2; ++c) {
    half8 f;
    #pragma unroll
    for (int j = 0; j < 8; ++j) {
      const int k = (fcbase + c) * 32 + quad * 8 + j;
      f[j] = (_Float16)((n16 < 7) ? Wfc[n16 * H_ + k] : 0.0f);
    }
    wfc[c] = f;
  }

  // ---- phase 0: preload all x for this WG into LDS (f16), zero pads ----
  for (int idx = tid; idx < T_ * 2 * 16; idx += 512) {
    const int t  = idx >> 5;
    const int rw = (idx >> 4) & 1;
    const int ii = idx & 15;
    float v = 0.0f;
    if (ii < I_) v = x[((size_t)t * B_ + wgb + rw) * I_ + ii];
    xlds[t][rw][ii] = (_Float16)v;
  }
  for (int idx = tid; idx < 2 * 2 * 168; idx += 512)
    ((_Float16*)abuf)[idx] = (_Float16)0.0f;
  __syncthreads();

  float c_state = 0.0f;           // lanes 0..31: cell (row=quad, j=16w+n16)
  const bool aload = (n16 == 0) || (n16 == 4);
  const int  arow  = n16 >> 2;

  half8 af[5];
  {
    half8 z;
    #pragma unroll
    for (int j = 0; j < 8; ++j) z[j] = (_Float16)0.0f;
    #pragma unroll
    for (int kc = 0; kc < 5; ++kc) af[kc] = z;
  }

  // acc regs 1..3 stay 0 forever (A rows 1..3,5..15 are zero -> D regs 1..3
  // never change). Only reg 0 is ever reset/used.
  float4_ acc[4];
  #pragma unroll
  for (int ti = 0; ti < 4; ++ti)
    #pragma unroll
    for (int r = 0; r < 4; ++r) acc[ti][r] = 0.0f;
  float4_ accf;
  #pragma unroll
  for (int r = 0; r < 4; ++r) accf[r] = 0.0f;

  // pre-loop: charge acc with xpart for step 0 (bias + x_0 * Wih)
  if (aload && quad < 2)
    af[4] = *(const half8*)&xlds[0][arow][quad * 8];
  #pragma unroll
  for (int ti = 0; ti < 4; ++ti) {
    acc[ti][0] = biasv[ti];
    acc[ti] = __builtin_amdgcn_mfma_f32_16x16x32_f16(af[4], wfrag[ti][4], acc[ti], 0, 0, 0);
  }

  // ---- phase 1: the recurrence. No vector-memory ops in this loop. ----
  for (int t = 0; t <= T_; ++t) {
    // h fragments for this step; x fragment for step t+1 (consumed at bottom)
    if (aload) {
      #pragma unroll
      for (int kc = 0; kc < 4; ++kc)
        af[kc] = *(const half8*)&abuf[t & 1][arow][kc * 32 + quad * 8];
      if (quad < 2 && (t + 1) < T_)
        af[4] = *(const half8*)&xlds[t + 1][arow][quad * 8];
    }

    if (t < T_) {
      // gates: only the 4 h K-chunks remain on the critical path
      #pragma unroll
      for (int kc = 0; kc < 4; ++kc) {
        #pragma unroll
        for (int ti = 0; ti < 4; ++ti)
          acc[ti] = __builtin_amdgcn_mfma_f32_16x16x32_f16(af[kc], wfrag[ti][kc], acc[ti], 0, 0, 0);
      }
      // cell update from accumulators (lanes 0..31, reg 0;
      // D row = quad*4 + reg -> rows 0,4 = batch rows 0,1)
      if (lane < 32) {
        const float iv = sigmoid_f(acc[0][0]);
        const float fv = sigmoid_f(acc[1][0]);
        const float gv = tanh_f(acc[2][0]);
        const float ov = sigmoid_f(acc[3][0]);
        c_state = fv * c_state + iv * gv;
        const float hv = ov * tanh_f(c_state);
        abuf[(t + 1) & 1][quad][16 * wave + n16] = (_Float16)hv;
      }
      // recharge acc with xpart for step t+1 (dead regs after the update)
      if (t + 1 < T_) {
        #pragma unroll
        for (int ti = 0; ti < 4; ++ti) {
          acc[ti][0] = biasv[ti];
          acc[ti] = __builtin_amdgcn_mfma_f32_16x16x32_f16(af[4], wfrag[ti][4], acc[ti], 0, 0, 0);
        }
      }
    }

    // FC partials: af holds h_t here -> logits for output row t-1.
    // wave 5: chunks 0,1 (+bias); wave 6: chunks 2,3. f16 partials.
    if ((wave == 5 || wave == 6) && t >= 1) {
      accf[0] = biasfc;
      accf = __builtin_amdgcn_mfma_f32_16x16x32_f16(af[fcbase],     wfc[0], accf, 0, 0, 0);
      accf = __builtin_amdgcn_mfma_f32_16x16x32_f16(af[fcbase + 1], wfc[1], accf, 0, 0, 0);
      if (lane < 32 && n16 < 7)
        lgring[t - 1][quad][(wave - 5) * 8 + n16] = (_Float16)accf[0];
    }

    __syncthreads();
  }

  // ---- phase 2: softmax of all 2048 logit rows (sum the two halves) ----
  for (int r = tid; r < T_ * 2; r += 512) {
    const int t = r >> 1;
    const int b = r & 1;
    float lg[7];
    float mx = -3.0e38f;
    #pragma unroll
    for (int k = 0; k < 7; ++k) {
      lg[k] = (float)lgring[t][b][k] + (float)lgring[t][b][8 + k];
      mx = fmaxf(mx, lg[k]);
    }
    float s = 0.0f;
    #pragma unroll
    for (int k = 0; k < 7; ++k) {
      lg[k] = fast_exp2(LOG2E * (lg[k] - mx));
      s += lg[k];
    }
    const float rs = fast_rcp(s);
    float* op = &out[((size_t)t * B_ + wgb + b) * 7];
    #pragma unroll
    for (int k = 0; k < 7; ++k) op[k] = lg[k] * rs;
  }
}

extern "C" void kernel_launch(void* const* d_in, const int* in_sizes, int n_in,
                              void* d_out, int out_size, void* d_ws, size_t ws_size,
                              hipStream_t stream) {
  (void)in_sizes; (void)n_in; (void)out_size; (void)d_ws; (void)ws_size;
  const float* x   = (const float*)d_in[0];
  const float* Wih = (const float*)d_in[1];
  const float* Whh = (const float*)d_in[2];
  const float* bih = (const float*)d_in[3];
  const float* bhh = (const float*)d_in[4];
  const float* Wfc = (const float*)d_in[5];
  const float* bfc = (const float*)d_in[6];
  hipLaunchKernelGGL(lstm_fused, dim3(256), dim3(512), 0, stream,
                     x, Wih, Whh, bih, bhh, Wfc, bfc, (float*)d_out);
}

// Round 8
// 2238.963 us; speedup vs baseline: 2.3276x; 2.3276x over previous
//
#include <hip/hip_runtime.h>

#define H_ 128
#define T_ 1024
#define B_ 512
#define I_ 13
#define LOG2E 1.4426950408889634f

typedef _Float16 half8 __attribute__((ext_vector_type(8)));
typedef float float4_ __attribute__((ext_vector_type(4)));

static __device__ __forceinline__ float fast_rcp(float v) {
  return __builtin_amdgcn_rcpf(v);
}
static __device__ __forceinline__ float fast_exp2(float v) {
  return __builtin_amdgcn_exp2f(v);
}
static __device__ __forceinline__ float sigmoid_f(float v) {
  return fast_rcp(1.0f + fast_exp2(-LOG2E * v));
}
static __device__ __forceinline__ float tanh_f(float v) {
  return 2.0f * fast_rcp(1.0f + fast_exp2(-2.0f * LOG2E * v)) - 1.0f;
}

// One WG per CU (256 WGs), 2 batch rows each, weights VGPR-resident.
// R8 = R7 intent, compile-fixed (macro -> always-inline lambda):
//  - R5 zero-VMEM skeleton (941 us verified)
//  - FC split waves 5/6 (2 K-chunks each, f16 partials; math verified in R6)
//  - t-loop unrolled by 2 (hard-coded ping-pong buffers, no t&1 math)
//  - hoisted per-lane LDS pointers
// Lesson from R6: accumulators must be DEAD at the barrier (loop-carrying
// acc across __syncthreads tripled VALU from AGPR shuffling).
__global__ __launch_bounds__(512, 1) void lstm_fused(
    const float* __restrict__ x, const float* __restrict__ Wih,
    const float* __restrict__ Whh, const float* __restrict__ bih,
    const float* __restrict__ bhh, const float* __restrict__ Wfc,
    const float* __restrict__ bfc, float* __restrict__ out)
{
  // 64 KB: x(t) for both rows, slots 13..15 zero (pad to k-chunk width)
  __shared__ __align__(16) _Float16 xlds[T_][2][16];
  // 64 KB: logits ring, f16: [t][row][part*8 + k], parts summed in phase 2
  __shared__ __align__(16) _Float16 lgring[T_][2][16];
  // 1.3 KB: double-buffered h (cols 0..127 used; stride 168 halfs)
  __shared__ __align__(16) _Float16 abuf[2][2][168];

  const int tid  = threadIdx.x;
  const int wave = tid >> 6;
  const int lane = tid & 63;
  const int n16  = lane & 15;
  const int quad = lane >> 4;
  const int wgb  = blockIdx.x * 2;

  // ---- W fragments: wave w owns gate tiles {w, w+8, w+16, w+24} ----
  // B layout (16x16x32): lane holds B[k = quad*8 + j][n = n16]
  half8 wfrag[4][5];
  float biasv[4];
  #pragma unroll
  for (int ti = 0; ti < 4; ++ti) {
    const int col = (wave + 8 * ti) * 16 + n16;
    biasv[ti] = bih[col] + bhh[col];
    #pragma unroll
    for (int kc = 0; kc < 5; ++kc) {
      half8 f;
      #pragma unroll
      for (int j = 0; j < 8; ++j) {
        const int k = kc * 32 + quad * 8 + j;
        float v = 0.0f;
        if (k < 128)            v = Whh[col * H_ + k];
        else if (k < 128 + I_)  v = Wih[col * I_ + (k - 128)];
        f[j] = (_Float16)v;
      }
      wfrag[ti][kc] = f;
    }
  }
  // FC: wave 5 owns K-chunks 0,1 (and the bias); wave 6 owns K-chunks 2,3.
  const int fcbase = (wave == 6) ? 2 : 0;
  half8 wfc[2];
  const float biasfc = (wave == 5 && n16 < 7) ? bfc[n16] : 0.0f;
  #pragma unroll
  for (int c = 0; c < 2; ++c) {
    half8 f;
    #pragma unroll
    for (int j = 0; j < 8; ++j) {
      const int k = (fcbase + c) * 32 + quad * 8 + j;
      f[j] = (_Float16)((n16 < 7) ? Wfc[n16 * H_ + k] : 0.0f);
    }
    wfc[c] = f;
  }

  // ---- phase 0: preload all x for this WG into LDS (f16), zero pads ----
  for (int idx = tid; idx < T_ * 2 * 16; idx += 512) {
    const int t  = idx >> 5;
    const int rw = (idx >> 4) & 1;
    const int ii = idx & 15;
    float v = 0.0f;
    if (ii < I_) v = x[((size_t)t * B_ + wgb + rw) * I_ + ii];
    xlds[t][rw][ii] = (_Float16)v;
  }
  for (int idx = tid; idx < 2 * 2 * 168; idx += 512)
    ((_Float16*)abuf)[idx] = (_Float16)0.0f;
  __syncthreads();

  float c_state = 0.0f;           // lanes 0..31: cell (row=quad, j=16w+n16)
  const bool aload = (n16 == 0) || (n16 == 4);
  const int  arow  = n16 >> 2;
  const bool upd   = (lane < 32);
  const bool fcw   = (wave == 5) || (wave == 6);

  // hoisted per-lane LDS pointers
  const _Float16* hrd0 = &abuf[0][arow][quad * 8];   // h chunks, buffer 0
  const _Float16* hrd1 = &abuf[1][arow][quad * 8];   // h chunks, buffer 1
  _Float16* hwr0 = &abuf[0][quad][16 * wave + n16];  // h write, buffer 0
  _Float16* hwr1 = &abuf[1][quad][16 * wave + n16];
  const _Float16* xp = &xlds[0][arow][quad * 8];     // +32 halfs per step
  _Float16* lgw = &lgring[0][quad][(wave - 5) * 8 + n16]; // +32 per step

  half8 af[5];
  {
    half8 z;
    #pragma unroll
    for (int j = 0; j < 8; ++j) z[j] = (_Float16)0.0f;
    #pragma unroll
    for (int kc = 0; kc < 5; ++kc) af[kc] = z;
  }

  // one LSTM step: read h from rd, write h to wr. doFC covers t>=1.
  auto lstm_step = [&](bool doFC, const _Float16* rd, _Float16* wr)
      __attribute__((always_inline)) {
    if (aload) {
      af[0] = *(const half8*)(rd);
      af[1] = *(const half8*)(rd + 32);
      af[2] = *(const half8*)(rd + 64);
      af[3] = *(const half8*)(rd + 96);
      if (quad < 2) af[4] = *(const half8*)xp;
    }
    float4_ acc[4];
    #pragma unroll
    for (int ti = 0; ti < 4; ++ti) {
      acc[ti][0] = biasv[ti];
      acc[ti][1] = 0.0f; acc[ti][2] = 0.0f; acc[ti][3] = 0.0f;
    }
    #pragma unroll
    for (int kc = 0; kc < 5; ++kc) {
      #pragma unroll
      for (int ti = 0; ti < 4; ++ti)
        acc[ti] = __builtin_amdgcn_mfma_f32_16x16x32_f16(af[kc],
                      wfrag[ti][kc], acc[ti], 0, 0, 0);
    }
    if (upd) {
      const float iv = sigmoid_f(acc[0][0]);
      const float fv = sigmoid_f(acc[1][0]);
      const float gv = tanh_f(acc[2][0]);
      const float ov = sigmoid_f(acc[3][0]);
      c_state = fv * c_state + iv * gv;
      *wr = (_Float16)(ov * tanh_f(c_state));
    }
    if (doFC && fcw) {
      float4_ accf;
      accf[0] = biasfc; accf[1] = 0.0f; accf[2] = 0.0f; accf[3] = 0.0f;
      accf = __builtin_amdgcn_mfma_f32_16x16x32_f16(af[fcbase],
                 wfc[0], accf, 0, 0, 0);
      accf = __builtin_amdgcn_mfma_f32_16x16x32_f16(af[fcbase + 1],
                 wfc[1], accf, 0, 0, 0);
      if (upd && n16 < 7) *(lgw - 32) = (_Float16)accf[0];
    }
    xp  += 32;
    lgw += 32;
    __syncthreads();
  };

  // ---- phase 1: the recurrence, unrolled by 2. No VMEM in this loop. ----
  lstm_step(false, hrd0, hwr1);
  lstm_step(true,  hrd1, hwr0);
  for (int t = 2; t < T_; t += 2) {
    lstm_step(true, hrd0, hwr1);
    lstm_step(true, hrd1, hwr0);
  }
  // epilogue: FC for h(T) (lives in buffer 0 since T is even)
  {
    if (aload) {
      af[0] = *(const half8*)(hrd0);
      af[1] = *(const half8*)(hrd0 + 32);
      af[2] = *(const half8*)(hrd0 + 64);
      af[3] = *(const half8*)(hrd0 + 96);
    }
    if (fcw) {
      float4_ accf;
      accf[0] = biasfc; accf[1] = 0.0f; accf[2] = 0.0f; accf[3] = 0.0f;
      accf = __builtin_amdgcn_mfma_f32_16x16x32_f16(af[fcbase], wfc[0], accf, 0, 0, 0);
      accf = __builtin_amdgcn_mfma_f32_16x16x32_f16(af[fcbase + 1], wfc[1], accf, 0, 0, 0);
      if (upd && n16 < 7)
        lgring[T_ - 1][quad][(wave - 5) * 8 + n16] = (_Float16)accf[0];
    }
    __syncthreads();
  }

  // ---- phase 2: softmax of all 2048 logit rows (sum the two halves) ----
  for (int r = tid; r < T_ * 2; r += 512) {
    const int t = r >> 1;
    const int b = r & 1;
    float lg[7];
    float mx = -3.0e38f;
    #pragma unroll
    for (int k = 0; k < 7; ++k) {
      lg[k] = (float)lgring[t][b][k] + (float)lgring[t][b][8 + k];
      mx = fmaxf(mx, lg[k]);
    }
    float s = 0.0f;
    #pragma unroll
    for (int k = 0; k < 7; ++k) {
      lg[k] = fast_exp2(LOG2E * (lg[k] - mx));
      s += lg[k];
    }
    const float rs = fast_rcp(s);
    float* op = &out[((size_t)t * B_ + wgb + b) * 7];
    #pragma unroll
    for (int k = 0; k < 7; ++k) op[k] = lg[k] * rs;
  }
}

extern "C" void kernel_launch(void* const* d_in, const int* in_sizes, int n_in,
                              void* d_out, int out_size, void* d_ws, size_t ws_size,
                              hipStream_t stream) {
  (void)in_sizes; (void)n_in; (void)out_size; (void)d_ws; (void)ws_size;
  const float* x   = (const float*)d_in[0];
  const float* Wih = (const float*)d_in[1];
  const float* Whh = (const float*)d_in[2];
  const float* bih = (const float*)d_in[3];
  const float* bhh = (const float*)d_in[4];
  const float* Wfc = (const float*)d_in[5];
  const float* bfc = (const float*)d_in[6];
  hipLaunchKernelGGL(lstm_fused, dim3(256), dim3(512), 0, stream,
                     x, Wih, Whh, bih, bhh, Wfc, bfc, (float*)d_out);
}